// Round 10
// baseline (6247.975 us; speedup 1.0000x reference)
//
#include <hip/hip_runtime.h>
#include <hip/hip_fp16.h>

typedef __attribute__((ext_vector_type(2))) _Float16 half2v;
typedef __attribute__((ext_vector_type(2))) __fp16   fp16x2;

#define SEQ     512
#define THREADS 512

// ws layout (uint4 units): Wq col-packed [64][512] @0; Wx [64][1536] @32768; Wh @131072
#define WQ_OFF   0
#define WX_OFF   32768
#define WH_OFF   131072
#define SYNC_OFF 3670016
// sync region (bytes): flagH u32[512]@0 ; flagS u32[512]@2048 ;
// Hbuf u32[2][64][256]@4096 (131072) ; Pbuf f32[2][16][32][12]@135168 (49152) ;
// pooled f32[64][512]@184320 ; fc1 f32[64][512]@315392 ;
// flagP u32[256]@446464 ; flagF u32[256]@447488   (epilogue-only, DISJOINT from loop flags)

__device__ inline unsigned int pack2f16(float a, float b) {
    fp16x2 p = __builtin_amdgcn_cvt_pkrtz(a, b);
    return __builtin_bit_cast(unsigned int, p);
}
__device__ inline float fdot2u(unsigned int a, unsigned int b, float acc) {
    return __builtin_amdgcn_fdot2(__builtin_bit_cast(half2v, a),
                                  __builtin_bit_cast(half2v, b), acc, false);
}
__device__ inline float dot4(uint4 h, uint4 w, float acc) {
    acc = fdot2u(h.x, w.x, acc); acc = fdot2u(h.y, w.y, acc);
    acc = fdot2u(h.z, w.z, acc); acc = fdot2u(h.w, w.w, acc);
    return acc;
}
__device__ inline float fsigmoid(float x) { return 1.f / (1.f + __expf(-x)); }
__device__ inline float ftanhf(float x) {
    float e = __expf(-2.f * fabsf(x));
    float t = (1.f - e) / (1.f + e);
    return copysignf(t, x);
}
__device__ inline void vmem_fence() { asm volatile("s_waitcnt vmcnt(0)" ::: "memory"); }
__device__ inline unsigned a_ld(unsigned* p) {
    return __hip_atomic_load(p, __ATOMIC_RELAXED, __HIP_MEMORY_SCOPE_AGENT);
}
__device__ inline void a_st(unsigned* p, unsigned v) {
    __hip_atomic_store(p, v, __ATOMIC_RELAXED, __HIP_MEMORY_SCOPE_AGENT);
}
__device__ inline float a_ldf(float* p) {
    return __hip_atomic_load(p, __ATOMIC_RELAXED, __HIP_MEMORY_SCOPE_AGENT);
}
__device__ inline void a_stf(float* p, float v) {
    __hip_atomic_store(p, v, __ATOMIC_RELAXED, __HIP_MEMORY_SCOPE_AGENT);
}

__global__ __launch_bounds__(256)
void pack_weights(const float* __restrict__ Wq,
                  const float* __restrict__ Wx,
                  const float* __restrict__ Wh,
                  uint4* __restrict__ ws) {
    int tid = blockIdx.x * blockDim.x + threadIdx.x;  // 0 .. 229375
    const float* src; uint4* dst; int C, idx;
    if (tid < 64 * 512)                  { src = Wq; dst = ws;          C = 512;  idx = tid; }
    else if (tid < 64 * 512 + 64 * 1536) { src = Wx; dst = ws + WX_OFF; C = 1536; idx = tid - 64 * 512; }
    else                                 { src = Wh; dst = ws + WH_OFF; C = 1536; idx = tid - (64 * 512 + 64 * 1536); }
    int m4 = idx / C;
    int c  = idx - m4 * C;
    const float* s = src + (size_t)(m4 * 8) * C + c;
    uint4 o;
    o.x = pack2f16(s[0 * (size_t)C], s[1 * (size_t)C]);
    o.y = pack2f16(s[2 * (size_t)C], s[3 * (size_t)C]);
    o.z = pack2f16(s[4 * (size_t)C], s[5 * (size_t)C]);
    o.w = pack2f16(s[6 * (size_t)C], s[7 * (size_t)C]);
    dst[idx] = o;
}

// 256 blocks. xcd = blk&7, bid = blk>>3 (0..31). Block serves groups gA=2xcd, gB=2xcd+1
// (4 batches each, XCD-local). Block owns cols [bid*16,+16) of each weight slice.
// Phases per step: X(A) X(B) Y(A) Y(B) Z(A) Z(B) — each group's sync RTs hide
// under the other group's compute.
__global__ __launch_bounds__(THREADS)
void gru_scan(const int* __restrict__ xtok, const float* __restrict__ emb,
              const uint4* __restrict__ wsp, const float* __restrict__ bx,
              const float* __restrict__ bh, const float* __restrict__ W1,
              const float* __restrict__ b1, const float* __restrict__ W2,
              const float* __restrict__ b2, float* __restrict__ out)
{
    const int blk  = blockIdx.x;
    const int xcd  = blk & 7;
    const int bid  = blk >> 3;          // 0..31
    const int gA   = xcd * 2;
    const int gB   = xcd * 2 + 1;
    const int tid  = threadIdx.x;
    const int lane = tid & 63;
    const int w    = tid >> 6;
    const int colsub = lane & 7;
    const int bp     = (lane >> 3) & 3;
    const int chsub  = lane >> 5;

    char* syncb = (char*)wsp + SYNC_OFF;
    unsigned* flagH = (unsigned*)syncb;
    unsigned* flagS = (unsigned*)(syncb + 2048);
    unsigned* Hbuf  = (unsigned*)(syncb + 4096);
    float* Pbuf     = (float*)(syncb + 135168);
    float* pooled_g = (float*)(syncb + 184320);
    float* fc1_g    = (float*)(syncb + 315392);
    unsigned* flagP = (unsigned*)(syncb + 446464);
    unsigned* flagF = (unsigned*)(syncb + 447488);

    __shared__ uint4 lds_W  [64][64];        // cols 0..15 Wq, 16..63 Wh (r,z,n x16)
    __shared__ uint4 lds_Wx [64][48];        // Wx (r,z,n x16)
    __shared__ uint4 lds_win[2][4][65];      // window row t per group/batch (padded)
    __shared__ uint4 lds_hb [4][65];         // shared h staging (one group at a time)
    __shared__ unsigned u_pk  [2][3][8][48][2]; // win@Wx per-head partials, f16 (b,b+2)
    __shared__ unsigned redH_pk[2][8][48][2];   // gh partials, f16 (b,b+2)
    __shared__ float redQf[640];             // [8][16][5] GEMM-q partials
    __shared__ float ghs[240], gxs[240];     // [48][5] combined sums
    __shared__ float a_all[2][4][8][3];

    // ---- persistent weight slices -> LDS ----
    for (int i = tid; i < 64 * 64; i += THREADS) {
        int ch = i >> 6, cl = i & 63;
        uint4 v;
        if (cl < 16) v = wsp[WQ_OFF + ch * 512 + bid * 16 + cl];
        else { int g = (cl - 16) >> 4, c = (cl - 16) & 15;
               v = wsp[WH_OFF + ch * 1536 + g * 512 + bid * 16 + c]; }
        lds_W[ch][cl] = v;
    }
    for (int i = tid; i < 64 * 48; i += THREADS) {
        int ch = i / 48, cl = i - ch * 48;
        int g = cl >> 4, c = cl & 15;
        lds_Wx[ch][cl] = wsp[WX_OFF + ch * 1536 + g * 512 + bid * 16 + c];
    }

    float bxr = 0, bxz = 0, bxn = 0, bhr = 0, bhz = 0, bhn = 0;
    if (tid < 128) {
        int m = (tid & 63) >> 2, cg = bid * 16 + m;
        bxr = bx[cg]; bxz = bx[512 + cg]; bxn = bx[1024 + cg];
        bhr = bh[cg]; bhz = bh[512 + cg]; bhn = bh[1024 + cg];
    }

    // wave duty: group wg = w>>2, batch wb = w&3 (window rows)
    const int wg  = w >> 2;
    const int wb  = w & 3;
    const int gbw = (xcd * 2 + wg) * 4 + wb;

    // pre-loop: stage win row 0 both groups; zero u_pk slots 1,2
    {
        int tk = xtok[gbw * SEQ];
        const float4* p = (const float4*)(emb + (size_t)tk * 512 + lane * 8);
        float4 ra = p[0], rb = p[1];
        uint4 pk;
        pk.x = pack2f16(ra.x, ra.y); pk.y = pack2f16(ra.z, ra.w);
        pk.z = pack2f16(rb.x, rb.y); pk.w = pack2f16(rb.z, rb.w);
        lds_win[wg][wb][lane] = pk;
        unsigned* up = &u_pk[0][0][0][0][0];
        for (int i = tid; i < 2 * 1536; i += THREADS) {
            int G = i / 1536, off = i - G * 1536;
            up[G * 2304 + 768 + off] = 0u;
        }
    }
    float hprev = 0.f, pooledv = 0.f;
    __syncthreads();

    for (int t = 0; t < SEQ; ++t) {
        const int par  = t & 1;
        const int slot = t % 3;

        // ---- prefetch win row t+1 (all waves) ----
        int tnext = (t + 1 < SEQ) ? t + 1 : t;
        int tkn = xtok[gbw * SEQ + tnext];
        const float4* pn = (const float4*)(emb + (size_t)tkn * 512 + lane * 8);
        float4 r3a = pn[0], r3b = pn[1];

        // ---- prefetch winv: wave0 lanes 0-11 -> A, lanes 32-43 -> B ----
        float winv[16];
        int b3 = 0, g3 = 0, trow = -1, sgrp = -1;
        if (w == 0) {
            int l = -1;
            if (lane < 12)                     { sgrp = 0; l = lane; }
            else if (lane >= 32 && lane < 44)  { sgrp = 1; l = lane - 32; }
            if (sgrp >= 0) {
                b3 = l / 3; g3 = l - b3 * 3; trow = t - 2 + g3;
                int gg = xcd * 2 + sgrp;
                int tok = (trow >= 0) ? xtok[(gg * 4 + b3) * SEQ + trow] : -1;
                if (tok >= 0) {
                    const float* er = emb + (size_t)tok * 512 + bid * 16;
                    #pragma unroll
                    for (int d = 0; d < 16; ++d) winv[d] = er[d];
                } else {
                    #pragma unroll
                    for (int d = 0; d < 16; ++d) winv[d] = 0.f;
                }
            }
        }

        uint4 hregA, hregB;

        // ======== X(A): poll flagH_A || U_A ; issue h_A loads ========
        if (w == 0) {
            bool done = lane >= 32;
            while (!__all(done)) {
                if (!done) done = (a_ld(&flagH[gA * 32 + lane]) >= (unsigned)t);
                if (!__all(done)) __builtin_amdgcn_s_sleep(1);
            }
        } else {
            #pragma unroll 1
            for (int rep = 0; rep < 2; ++rep) {
                int k = (rep == 0) ? w : 0;
                if (rep == 1 && w != 7) break;
                float acu[6];
                #pragma unroll
                for (int i = 0; i < 6; ++i) acu[i] = 0.f;
                int ch0 = k * 8 + chsub * 4;
                #pragma unroll
                for (int i = 0; i < 4; ++i) {
                    uint4 c0 = lds_win[0][bp][ch0 + i];
                    #pragma unroll
                    for (int j = 0; j < 6; ++j)
                        acu[j] = dot4(c0, lds_Wx[ch0 + i][colsub + 8 * j], acu[j]);
                }
                #pragma unroll
                for (int j = 0; j < 6; ++j) {
                    acu[j] += __shfl_xor(acu[j], 32);
                    float hi = __shfl_down(acu[j], 16);
                    if (chsub == 0 && bp < 2)
                        u_pk[0][slot][k][colsub + 8 * j][bp] = pack2f16(acu[j], hi);
                }
            }
        }
        __syncthreads();
        if (tid < 256) {
            int bb = tid >> 6, ch = tid & 63;
            unsigned* s = Hbuf + (size_t)(par ^ 1) * 16384 + (gA * 4 + bb) * 256 + ch * 4;
            hregA.x = a_ld(s); hregA.y = a_ld(s + 1); hregA.z = a_ld(s + 2); hregA.w = a_ld(s + 3);
        }

        // ======== X(B): poll flagH_B || U_B ; issue h_B loads ========
        if (w == 0) {
            bool done = lane >= 32;
            while (!__all(done)) {
                if (!done) done = (a_ld(&flagH[gB * 32 + lane]) >= (unsigned)t);
                if (!__all(done)) __builtin_amdgcn_s_sleep(1);
            }
        } else {
            #pragma unroll 1
            for (int rep = 0; rep < 2; ++rep) {
                int k = (rep == 0) ? w : 0;
                if (rep == 1 && w != 7) break;
                float acu[6];
                #pragma unroll
                for (int i = 0; i < 6; ++i) acu[i] = 0.f;
                int ch0 = k * 8 + chsub * 4;
                #pragma unroll
                for (int i = 0; i < 4; ++i) {
                    uint4 c0 = lds_win[1][bp][ch0 + i];
                    #pragma unroll
                    for (int j = 0; j < 6; ++j)
                        acu[j] = dot4(c0, lds_Wx[ch0 + i][colsub + 8 * j], acu[j]);
                }
                #pragma unroll
                for (int j = 0; j < 6; ++j) {
                    acu[j] += __shfl_xor(acu[j], 32);
                    float hi = __shfl_down(acu[j], 16);
                    if (chsub == 0 && bp < 2)
                        u_pk[1][slot][k][colsub + 8 * j][bp] = pack2f16(acu[j], hi);
                }
            }
        }
        __syncthreads();
        if (tid < 256) {
            int bb = tid >> 6, ch = tid & 63;
            unsigned* s = Hbuf + (size_t)(par ^ 1) * 16384 + (gB * 4 + bb) * 256 + ch * 4;
            hregB.x = a_ld(s); hregB.y = a_ld(s + 1); hregB.z = a_ld(s + 2); hregB.w = a_ld(s + 3);
        }

        // ======== Y(A) ========
        if (tid < 256) lds_hb[tid >> 6][tid & 63] = hregA;
        __syncthreads();
        {   // GEMM-q A
            float aq0 = 0, aq1 = 0;
            int ch0 = w * 8 + chsub * 4;
            #pragma unroll
            for (int i = 0; i < 4; ++i) {
                uint4 h0 = lds_hb[bp][ch0 + i];
                aq0 = dot4(h0, lds_W[ch0 + i][colsub],     aq0);
                aq1 = dot4(h0, lds_W[ch0 + i][colsub + 8], aq1);
            }
            aq0 += __shfl_xor(aq0, 32); aq1 += __shfl_xor(aq1, 32);
            if (chsub == 0) {
                redQf[w * 80 + colsub * 5 + bp]       = aq0;
                redQf[w * 80 + (colsub + 8) * 5 + bp] = aq1;
            }
        }
        __syncthreads();
        if (w == 0) {   // scores A + early publish
            if (sgrp == 0) {
                float s = 0.f;
                if (trow >= 0) {
                    #pragma unroll
                    for (int d = 0; d < 16; ++d) {
                        float q = redQf[d * 5 + b3];
                        #pragma unroll
                        for (int k = 1; k < 8; ++k) q += redQf[k * 80 + d * 5 + b3];
                        s += winv[d] * q;
                    }
                }
                a_stf(&Pbuf[((size_t)(par * 16 + gA) * 32 + bid) * 12 + b3 * 3 + g3], s);
            }
            vmem_fence();
            if (lane == 0) a_st(&flagS[gA * 32 + bid], (unsigned)(t + 1));
        } else {        // gh A
            #pragma unroll 1
            for (int rep = 0; rep < 2; ++rep) {
                int k = (rep == 0) ? w : 0;
                if (rep == 1 && w != 7) break;
                float ag[6];
                #pragma unroll
                for (int i = 0; i < 6; ++i) ag[i] = 0.f;
                int ch0 = k * 8 + chsub * 4;
                #pragma unroll
                for (int i = 0; i < 4; ++i) {
                    uint4 h0 = lds_hb[bp][ch0 + i];
                    #pragma unroll
                    for (int j = 0; j < 6; ++j)
                        ag[j] = dot4(h0, lds_W[ch0 + i][16 + colsub + 8 * j], ag[j]);
                }
                #pragma unroll
                for (int j = 0; j < 6; ++j) {
                    ag[j] += __shfl_xor(ag[j], 32);
                    float hi = __shfl_down(ag[j], 16);
                    if (chsub == 0 && bp < 2)
                        redH_pk[0][k][colsub + 8 * j][bp] = pack2f16(ag[j], hi);
                }
            }
        }

        // ======== Y(B) ========
        __syncthreads();
        if (tid < 256) lds_hb[tid >> 6][tid & 63] = hregB;
        __syncthreads();
        {   // GEMM-q B
            float aq0 = 0, aq1 = 0;
            int ch0 = w * 8 + chsub * 4;
            #pragma unroll
            for (int i = 0; i < 4; ++i) {
                uint4 h0 = lds_hb[bp][ch0 + i];
                aq0 = dot4(h0, lds_W[ch0 + i][colsub],     aq0);
                aq1 = dot4(h0, lds_W[ch0 + i][colsub + 8], aq1);
            }
            aq0 += __shfl_xor(aq0, 32); aq1 += __shfl_xor(aq1, 32);
            if (chsub == 0) {
                redQf[w * 80 + colsub * 5 + bp]       = aq0;
                redQf[w * 80 + (colsub + 8) * 5 + bp] = aq1;
            }
        }
        __syncthreads();
        if (w == 0) {   // scores B + publish
            if (sgrp == 1) {
                float s = 0.f;
                if (trow >= 0) {
                    #pragma unroll
                    for (int d = 0; d < 16; ++d) {
                        float q = redQf[d * 5 + b3];
                        #pragma unroll
                        for (int k = 1; k < 8; ++k) q += redQf[k * 80 + d * 5 + b3];
                        s += winv[d] * q;
                    }
                }
                a_stf(&Pbuf[((size_t)(par * 16 + gB) * 32 + bid) * 12 + b3 * 3 + g3], s);
            }
            vmem_fence();
            if (lane == 0) a_st(&flagS[gB * 32 + bid], (unsigned)(t + 1));
        } else {        // gh B
            #pragma unroll 1
            for (int rep = 0; rep < 2; ++rep) {
                int k = (rep == 0) ? w : 0;
                if (rep == 1 && w != 7) break;
                float ag[6];
                #pragma unroll
                for (int i = 0; i < 6; ++i) ag[i] = 0.f;
                int ch0 = k * 8 + chsub * 4;
                #pragma unroll
                for (int i = 0; i < 4; ++i) {
                    uint4 h0 = lds_hb[bp][ch0 + i];
                    #pragma unroll
                    for (int j = 0; j < 6; ++j)
                        ag[j] = dot4(h0, lds_W[ch0 + i][16 + colsub + 8 * j], ag[j]);
                }
                #pragma unroll
                for (int j = 0; j < 6; ++j) {
                    ag[j] += __shfl_xor(ag[j], 32);
                    float hi = __shfl_down(ag[j], 16);
                    if (chsub == 0 && bp < 2)
                        redH_pk[1][k][colsub + 8 * j][bp] = pack2f16(ag[j], hi);
                }
            }
        }

        // ======== Z(A): wait scores A, softmax; stage win t+1; combine; pointwise ========
        if (w == 0) {
            bool done = lane >= 32;
            while (!__all(done)) {
                if (!done) done = (a_ld(&flagS[gA * 32 + lane]) >= (unsigned)(t + 1));
                if (!__all(done)) __builtin_amdgcn_s_sleep(1);
            }
            if (lane < 32) {
                int b = lane >> 3, n = lane & 7;
                float* base = Pbuf + (size_t)(par * 16 + gA) * 32 * 12;
                float s0 = 0, s1 = 0, s2 = 0;
                #pragma unroll
                for (int j = 0; j < 4; ++j) {
                    float* pj = base + (n * 4 + j) * 12 + b * 3;
                    s0 += a_ldf(pj); s1 += a_ldf(pj + 1); s2 += a_ldf(pj + 2);
                }
                s0 *= 0.125f; s1 *= 0.125f; s2 *= 0.125f;
                float mx = fmaxf(s0, fmaxf(s1, s2));
                float e0 = __expf(s0 - mx), e1 = __expf(s1 - mx), e2 = __expf(s2 - mx);
                float inv = 1.f / (e0 + e1 + e2);
                a_all[0][b][n][0] = e0 * inv; a_all[0][b][n][1] = e1 * inv; a_all[0][b][n][2] = e2 * inv;
            }
        }
        {   // stage win row t+1 (all waves)
            uint4 pk;
            pk.x = pack2f16(r3a.x, r3a.y); pk.y = pack2f16(r3a.z, r3a.w);
            pk.z = pack2f16(r3b.x, r3b.y); pk.w = pack2f16(r3b.z, r3b.w);
            lds_win[wg][wb][lane] = pk;
        }
        __syncthreads();
        if (tid < 192) {
            int col = tid >> 2, b = tid & 3;
            int bq = b & 1, hf = b >> 1;
            float ghsum = 0.f;
            #pragma unroll
            for (int k = 0; k < 8; ++k) {
                fp16x2 v = __builtin_bit_cast(fp16x2, redH_pk[0][k][col][bq]);
                ghsum += (float)v[hf];
            }
            float gxsum = 0.f;
            #pragma unroll
            for (int g = 0; g < 3; ++g) {
                int sg = (t + 1 + g) % 3;
                #pragma unroll
                for (int k = 0; k < 8; ++k) {
                    fp16x2 u = __builtin_bit_cast(fp16x2, u_pk[0][sg][k][col][bq]);
                    gxsum += a_all[0][b][k][g] * (float)u[hf];
                }
            }
            ghs[col * 5 + b] = ghsum;
            gxs[col * 5 + b] = gxsum;
        }
        __syncthreads();
        if (tid < 64) {
            int m = tid >> 2, b = tid & 3;
            float r = fsigmoid(gxs[m * 5 + b] + bxr + ghs[m * 5 + b] + bhr);
            float z = fsigmoid(gxs[(16 + m) * 5 + b] + bxz + ghs[(16 + m) * 5 + b] + bhz);
            float n = ftanhf(gxs[(32 + m) * 5 + b] + bxn + r * (ghs[(32 + m) * 5 + b] + bhn));
            float hnew = (1.f - z) * n + z * hprev;
            hprev = hnew; pooledv += hnew;
            float hnx = __shfl_down(hnew, 4);
            if (!(m & 1))
                a_st(&Hbuf[(size_t)par * 16384 + (gA * 4 + b) * 256 + bid * 8 + (m >> 1)],
                     pack2f16(hnew, hnx));
        }
        vmem_fence();
        __syncthreads();
        if (tid == 0) a_st(&flagH[gA * 32 + bid], (unsigned)(t + 1));

        // ======== Z(B) ========
        if (w == 0) {
            bool done = lane >= 32;
            while (!__all(done)) {
                if (!done) done = (a_ld(&flagS[gB * 32 + lane]) >= (unsigned)(t + 1));
                if (!__all(done)) __builtin_amdgcn_s_sleep(1);
            }
            if (lane < 32) {
                int b = lane >> 3, n = lane & 7;
                float* base = Pbuf + (size_t)(par * 16 + gB) * 32 * 12;
                float s0 = 0, s1 = 0, s2 = 0;
                #pragma unroll
                for (int j = 0; j < 4; ++j) {
                    float* pj = base + (n * 4 + j) * 12 + b * 3;
                    s0 += a_ldf(pj); s1 += a_ldf(pj + 1); s2 += a_ldf(pj + 2);
                }
                s0 *= 0.125f; s1 *= 0.125f; s2 *= 0.125f;
                float mx = fmaxf(s0, fmaxf(s1, s2));
                float e0 = __expf(s0 - mx), e1 = __expf(s1 - mx), e2 = __expf(s2 - mx);
                float inv = 1.f / (e0 + e1 + e2);
                a_all[1][b][n][0] = e0 * inv; a_all[1][b][n][1] = e1 * inv; a_all[1][b][n][2] = e2 * inv;
            }
        }
        __syncthreads();
        if (tid < 192) {
            int col = tid >> 2, b = tid & 3;
            int bq = b & 1, hf = b >> 1;
            float ghsum = 0.f;
            #pragma unroll
            for (int k = 0; k < 8; ++k) {
                fp16x2 v = __builtin_bit_cast(fp16x2, redH_pk[1][k][col][bq]);
                ghsum += (float)v[hf];
            }
            float gxsum = 0.f;
            #pragma unroll
            for (int g = 0; g < 3; ++g) {
                int sg = (t + 1 + g) % 3;
                #pragma unroll
                for (int k = 0; k < 8; ++k) {
                    fp16x2 u = __builtin_bit_cast(fp16x2, u_pk[1][sg][k][col][bq]);
                    gxsum += a_all[1][b][k][g] * (float)u[hf];
                }
            }
            ghs[col * 5 + b] = ghsum;
            gxs[col * 5 + b] = gxsum;
        }
        __syncthreads();
        if (tid >= 64 && tid < 128) {
            int m = (tid & 63) >> 2, b = (tid & 63) & 3;
            float r = fsigmoid(gxs[m * 5 + b] + bxr + ghs[m * 5 + b] + bhr);
            float z = fsigmoid(gxs[(16 + m) * 5 + b] + bxz + ghs[(16 + m) * 5 + b] + bhz);
            float n = ftanhf(gxs[(32 + m) * 5 + b] + bxn + r * (ghs[(32 + m) * 5 + b] + bhn));
            float hnew = (1.f - z) * n + z * hprev;
            hprev = hnew; pooledv += hnew;
            float hnx = __shfl_down(hnew, 4);
            if (!(m & 1))
                a_st(&Hbuf[(size_t)par * 16384 + (gB * 4 + b) * 256 + bid * 8 + (m >> 1)],
                     pack2f16(hnew, hnx));
        }
        vmem_fence();
        __syncthreads();
        if (tid == 0) a_st(&flagH[gB * 32 + bid], (unsigned)(t + 1));
    }

    // ======== epilogue: pooled -> relu -> FC1 -> FC2 (DISJOINT flagP/flagF) ========
    if (tid < 128) {
        int G = tid >> 6, l = tid & 63;
        int m = l >> 2, b = l & 3;
        int gb = (xcd * 2 + G) * 4 + b;
        a_stf(&pooled_g[(size_t)gb * 512 + bid * 16 + m], fmaxf(pooledv, 0.f));
    }
    vmem_fence();
    __syncthreads();
    if (tid == 0) a_st(&flagP[blk], 1u);
    if (w == 0) {
        bool done = lane >= 32;
        while (!__all(done)) {
            if (!done) done = (a_ld(&flagP[lane * 8 + xcd]) >= 1u);
            if (!__all(done)) __builtin_amdgcn_s_sleep(1);
        }
    }
    __syncthreads();

    float* stage = (float*)&lds_W[0][0];   // reuse weight LDS as [8][512]
    for (int i = tid; i < 8 * 512; i += THREADS) {
        int bb = i >> 9, k = i & 511;
        stage[i] = a_ldf(&pooled_g[(size_t)(xcd * 8 + bb) * 512 + k]);
    }
    __syncthreads();
    if (tid < 128) {
        int c = tid >> 3, bb = tid & 7;
        int cg = bid * 16 + c;
        const float* pr = stage + bb * 512;
        float acc1 = b1[cg];
        for (int k = 0; k < 512; ++k) acc1 += pr[k] * W1[(size_t)k * 512 + cg];
        a_stf(&fc1_g[(size_t)(xcd * 8 + bb) * 512 + cg], acc1);
    }
    vmem_fence();
    __syncthreads();
    if (tid == 0) a_st(&flagF[blk], 1u);

    if (bid == 0) {
        if (w == 0) {
            bool done = lane >= 32;
            while (!__all(done)) {
                if (!done) done = (a_ld(&flagF[lane * 8 + xcd]) >= 1u);
                if (!__all(done)) __builtin_amdgcn_s_sleep(1);
            }
        }
        __syncthreads();
        for (int i = tid; i < 8 * 512; i += THREADS) {
            int bb = i >> 9, k = i & 511;
            stage[i] = a_ldf(&fc1_g[(size_t)(xcd * 8 + bb) * 512 + k]);
        }
        __syncthreads();
        if (tid < 80) {
            int bb = tid / 10, cls = tid - bb * 10;
            const float* fr = stage + bb * 512;
            float a2 = b2[cls];
            for (int k = 0; k < 512; ++k) a2 += fr[k] * W2[k * 10 + cls];
            out[(xcd * 8 + bb) * 10 + cls] = a2;
        }
    }
}

extern "C" void kernel_launch(void* const* d_in, const int* in_sizes, int n_in,
                              void* d_out, int out_size, void* d_ws, size_t ws_size,
                              hipStream_t stream) {
    const int*   x   = (const int*)d_in[0];
    const float* emb = (const float*)d_in[1];
    const float* Wq  = (const float*)d_in[2];
    const float* Wx  = (const float*)d_in[3];
    const float* Wh  = (const float*)d_in[4];
    const float* bx  = (const float*)d_in[5];
    const float* bh  = (const float*)d_in[6];
    const float* W1  = (const float*)d_in[7];
    const float* b1  = (const float*)d_in[8];
    const float* W2  = (const float*)d_in[9];
    const float* b2  = (const float*)d_in[10];
    uint4* wsp = (uint4*)d_ws;
    float* outp = (float*)d_out;

    hipLaunchKernelGGL(pack_weights, dim3(896), dim3(256), 0, stream, Wq, Wx, Wh, wsp);
    hipMemsetAsync((char*)d_ws + SYNC_OFF, 0, 135168, stream);          // flagH/flagS/Hbuf
    hipMemsetAsync((char*)d_ws + SYNC_OFF + 446464, 0, 2048, stream);   // flagP/flagF

    void* args[] = { (void*)&x, (void*)&emb, (void*)&wsp, (void*)&bx, (void*)&bh,
                     (void*)&W1, (void*)&b1, (void*)&W2, (void*)&b2, (void*)&outp };
    hipError_t e = hipLaunchCooperativeKernel((void*)gru_scan, dim3(256), dim3(THREADS),
                                              args, 0, stream);
    if (e != hipSuccess) {
        hipLaunchKernelGGL(gru_scan, dim3(256), dim3(THREADS), 0, stream,
                           x, emb, wsp, bx, bh, W1, b1, W2, b2, outp);
    }
}

// Round 12
// 4839.180 us; speedup vs baseline: 1.2911x; 1.2911x over previous
//
#include <hip/hip_runtime.h>
#include <hip/hip_fp16.h>

typedef __attribute__((ext_vector_type(2))) _Float16 half2v;
typedef __attribute__((ext_vector_type(2))) __fp16   fp16x2;

#define SEQ     512
#define THREADS 512

// ws (uint4): Wx [64][1536] @0 ; Wh [64][1536] @98304 ; WqR rows [512][64] @196608
#define WX_OFF   0
#define WH_OFF   98304
#define WQR_OFF  196608
#define SYNC_OFF 3670016
// sync (bytes): flagH u32[256]@0 ; Hbuf u32[2][64][256]@1024 (131072) ;
// Pbuf f32[2][8][32][192]@132096 (393216) ; pooled f32[64][512]@525312 ;
// fc1 f32[64][512]@656384 ; end 787456

__device__ inline unsigned int pack2f16(float a, float b) {
    fp16x2 p = __builtin_amdgcn_cvt_pkrtz(a, b);
    return __builtin_bit_cast(unsigned int, p);
}
__device__ inline float fdot2u(unsigned int a, unsigned int b, float acc) {
    return __builtin_amdgcn_fdot2(__builtin_bit_cast(half2v, a),
                                  __builtin_bit_cast(half2v, b), acc, false);
}
__device__ inline float dot4(uint4 h, uint4 w, float acc) {
    acc = fdot2u(h.x, w.x, acc); acc = fdot2u(h.y, w.y, acc);
    acc = fdot2u(h.z, w.z, acc); acc = fdot2u(h.w, w.w, acc);
    return acc;
}
__device__ inline float fsigmoid(float x) { return 1.f / (1.f + __expf(-x)); }
__device__ inline float ftanhf(float x) {
    float e = __expf(-2.f * fabsf(x));
    float t = (1.f - e) / (1.f + e);
    return copysignf(t, x);
}
__device__ inline void vmem_fence() { asm volatile("s_waitcnt vmcnt(0)" ::: "memory"); }
__device__ inline unsigned a_ld(unsigned* p) {
    return __hip_atomic_load(p, __ATOMIC_RELAXED, __HIP_MEMORY_SCOPE_AGENT);
}
__device__ inline void a_st(unsigned* p, unsigned v) {
    __hip_atomic_store(p, v, __ATOMIC_RELAXED, __HIP_MEMORY_SCOPE_AGENT);
}
__device__ inline float a_ldf(float* p) {
    return __hip_atomic_load(p, __ATOMIC_RELAXED, __HIP_MEMORY_SCOPE_AGENT);
}
__device__ inline void a_stf(float* p, float v) {
    __hip_atomic_store(p, v, __ATOMIC_RELAXED, __HIP_MEMORY_SCOPE_AGENT);
}

__global__ __launch_bounds__(256)
void pack_weights(const float* __restrict__ Wq,
                  const float* __restrict__ Wx,
                  const float* __restrict__ Wh,
                  uint4* __restrict__ ws) {
    int tid = blockIdx.x * blockDim.x + threadIdx.x;  // 0..229375
    if (tid < 196608) {
        const float* src; uint4* dst; int idx;
        if (tid < 98304) { src = Wx; dst = ws + WX_OFF; idx = tid; }
        else             { src = Wh; dst = ws + WH_OFF; idx = tid - 98304; }
        int m4 = idx / 1536;
        int c  = idx - m4 * 1536;
        const float* s = src + (size_t)(m4 * 8) * 1536 + c;
        uint4 o;
        o.x = pack2f16(s[0 * 1536], s[1 * 1536]);
        o.y = pack2f16(s[2 * 1536], s[3 * 1536]);
        o.z = pack2f16(s[4 * 1536], s[5 * 1536]);
        o.w = pack2f16(s[6 * 1536], s[7 * 1536]);
        dst[idx] = o;
    } else {
        int idx = tid - 196608;            // 0..32767  Wq rows, d-pairs
        int m = idx >> 6, q = idx & 63;
        const float* s = Wq + (size_t)m * 512 + q * 8;
        uint4 o;
        o.x = pack2f16(s[0], s[1]); o.y = pack2f16(s[2], s[3]);
        o.z = pack2f16(s[4], s[5]); o.w = pack2f16(s[6], s[7]);
        ws[WQR_OFF + idx] = o;
    }
}

// 256 blocks. gid = blk&7 (XCD-local groups of 32), bid = blk>>3. Group owns
// batches 8*gid..+8; block owns gate cols [bid*16,+16) and Wq ROWS [bid*16,+16).
// ONE sync/step: publish (h(t), pscores(t+1)=h(t)·κ) under flagH.
// κ (rolling, new row only) + U (win@Wx) computed in the wait shadow.
__global__ __launch_bounds__(THREADS)
void gru_scan(const int* __restrict__ xtok, const float* __restrict__ emb,
              const uint4* __restrict__ wsp, const float* __restrict__ bx,
              const float* __restrict__ bh, const float* __restrict__ W1,
              const float* __restrict__ b1, const float* __restrict__ W2,
              const float* __restrict__ b2, float* __restrict__ out)
{
    const int blk  = blockIdx.x;
    const int gid  = blk & 7;
    const int bid  = blk >> 3;
    const int tid  = threadIdx.x;
    const int lane = tid & 63;
    const int w    = tid >> 6;
    const int colsub = lane & 7;
    const int bp     = (lane >> 3) & 3;
    const int chsub  = lane >> 5;

    char* syncb = (char*)wsp + SYNC_OFF;
    unsigned* flagH = (unsigned*)syncb;
    unsigned* Hbuf  = (unsigned*)(syncb + 1024);
    float* Pbuf     = (float*)(syncb + 132096);
    float* pooled_g = (float*)(syncb + 525312);
    float* fc1_g    = (float*)(syncb + 656384);

    __shared__ uint4 lds_Wh [64][48];       // Wh col-slice (r,z,n x16)
    __shared__ uint4 lds_Wx [64][48];       // Wx col-slice
    __shared__ uint4 lds_win[2][8][65];     // win rows, alternating t / t+1 (padded)
    __shared__ uint4 lds_h4 [8][65];        // h(t-1) f16 pairs (padded)
    __shared__ unsigned u_pk[3][8][48][4];  // win@Wx per-head partials, f16 (b,b+4)
    __shared__ unsigned kap[4][16][8][4];   // kappa f16 n-pairs [slot][m][b][np]
    __shared__ unsigned redH_pk[8][48][4];  // gh partials f16 (b,b+4)
    __shared__ float ghs[48][9];
    __shared__ float gxs[48][9];
    __shared__ float a_all[8][8][3];
    __shared__ float hsl[8][17];            // own h-slice f32 [b][m]

    // ---- persistent weight slices -> LDS ----
    for (int i = tid; i < 64 * 48; i += THREADS) {
        int ch = i / 48, cl = i - ch * 48;
        int g = cl >> 4, c = cl & 15;
        lds_Wh[ch][cl] = wsp[WH_OFF + ch * 1536 + g * 512 + bid * 16 + c];
        lds_Wx[ch][cl] = wsp[WX_OFF + ch * 1536 + g * 512 + bid * 16 + c];
    }
    const uint4* WqR = wsp + WQR_OFF + (size_t)bid * 16 * 64;   // 16 rows x 64 uint4

    float bxr = 0, bxz = 0, bxn = 0, bhr = 0, bhz = 0, bhn = 0;
    if (tid < 128) {
        int c = tid >> 3, cg = bid * 16 + c;
        bxr = bx[cg]; bxz = bx[512 + cg]; bxn = bx[1024 + cg];
        bhr = bh[cg]; bhz = bh[512 + cg]; bhn = bh[1024 + cg];
    }

    auto kappa_one = [&](int buf, int slot, int v) {
        int m = v >> 5, b = (v >> 2) & 7, np = v & 3;
        const uint4* wq = WqR + m * 64 + np * 16;
        float a0 = 0.f, a1 = 0.f;
        #pragma unroll
        for (int k = 0; k < 8; ++k) a0 = dot4(lds_win[buf][b][np * 16 + k], wq[k], a0);
        #pragma unroll
        for (int k = 0; k < 8; ++k) a1 = dot4(lds_win[buf][b][np * 16 + 8 + k], wq[8 + k], a1);
        kap[slot][m][b][np] = pack2f16(a0, a1);
    };

    const int gb = gid * 8 + w;   // wave w = batch w (window duty)

    // ---- pre-loop: stage row 0 -> buf0 ; load row 1 -> regs ; zero slots ; kappa(row0) ----
    float4 r1a, r1b;
    {
        int tk0 = xtok[gb * SEQ];
        const float4* p0 = (const float4*)(emb + (size_t)tk0 * 512 + lane * 8);
        float4 a = p0[0], b4 = p0[1];
        uint4 pk;
        pk.x = pack2f16(a.x, a.y); pk.y = pack2f16(a.z, a.w);
        pk.z = pack2f16(b4.x, b4.y); pk.w = pack2f16(b4.z, b4.w);
        lds_win[0][w][lane] = pk;
        int tk1 = xtok[gb * SEQ + ((1 < SEQ) ? 1 : 0)];
        const float4* p1 = (const float4*)(emb + (size_t)tk1 * 512 + lane * 8);
        r1a = p1[0]; r1b = p1[1];
        unsigned* up = &u_pk[0][0][0][0];
        for (int i = tid; i < 3072; i += THREADS) up[1536 + i] = 0u;   // u slots 1,2
        unsigned* kp = &kap[0][0][0][0];
        for (int i = tid; i < 1024; i += THREADS) kp[1024 + i] = 0u;   // kap slots 2,3
    }
    __syncthreads();
    kappa_one(0, 0, tid);    // kappa(row 0) -> slot 0, 512 values, 1/thread

    float hprev = 0.f, pooledv = 0.f;

    for (int t = 0; t < SEQ; ++t) {
        const int par   = t & 1;
        const int bufc  = t & 1;
        const int bufn  = (t + 1) & 1;
        const int uslot = t % 3;
        const int kslot = (t + 1) & 3;

        // ---- top: stage row t+1 (regs) -> lds_win[bufn]; issue load row t+2 ----
        {
            uint4 pk;
            pk.x = pack2f16(r1a.x, r1a.y); pk.y = pack2f16(r1a.z, r1a.w);
            pk.z = pack2f16(r1b.x, r1b.y); pk.w = pack2f16(r1b.z, r1b.w);
            lds_win[bufn][w][lane] = pk;
        }
        {
            int tn = (t + 2 < SEQ) ? t + 2 : SEQ - 1;
            int tk = xtok[gb * SEQ + tn];
            const float4* pn = (const float4*)(emb + (size_t)tk * 512 + lane * 8);
            r1a = pn[0]; r1b = pn[1];
        }
        __syncthreads();                                   // B1

        // ---- overlap: wave0 polls flagH ; waves1-7: U(row t) ; then kappa(row t+1) ----
        if (w == 0) {
            bool done = lane >= 32;
            while (!__all(done)) {
                if (!done) done = (a_ld(&flagH[gid * 32 + lane]) >= (unsigned)t);
                if (!__all(done)) __builtin_amdgcn_s_sleep(1);
            }
        } else {
            #pragma unroll 1
            for (int rep = 0; rep < 2; ++rep) {
                int k = (rep == 0) ? w : 0;
                if (rep == 1 && w != 7) break;
                float acu[12];
                #pragma unroll
                for (int i = 0; i < 12; ++i) acu[i] = 0.f;
                int ch0 = k * 8 + chsub * 4;
                #pragma unroll
                for (int i = 0; i < 4; ++i) {
                    int ch = ch0 + i;
                    uint4 c0 = lds_win[bufc][bp][ch], c1 = lds_win[bufc][bp + 4][ch];
                    #pragma unroll
                    for (int j = 0; j < 6; ++j) {
                        uint4 wv = lds_Wx[ch][colsub + 8 * j];
                        acu[j]     = dot4(c0, wv, acu[j]);
                        acu[6 + j] = dot4(c1, wv, acu[6 + j]);
                    }
                }
                #pragma unroll
                for (int i = 0; i < 12; ++i) acu[i] += __shfl_xor(acu[i], 32);
                if (chsub == 0) {
                    #pragma unroll
                    for (int j = 0; j < 6; ++j)
                        u_pk[uslot][k][colsub + 8 * j][bp] = pack2f16(acu[j], acu[6 + j]);
                }
            }
        }
        if (tid >= 64) {
            kappa_one(bufn, kslot, tid - 64);
            if (tid < 128) kappa_one(bufn, kslot, 448 + tid - 64);
        }
        __syncthreads();                                   // B2

        // ---- h-load ALL 8 batches (tid<256, 2 uint4 each) | pscore-sum+softmax (256..319) ----
        if (tid < 256) {
            int bb = tid >> 5, c2 = tid & 31;
            unsigned* s = Hbuf + (size_t)(par ^ 1) * 16384 + (gid * 8 + bb) * 256 + c2 * 4;
            uint4 v;
            v.x = a_ld(s); v.y = a_ld(s + 1); v.z = a_ld(s + 2); v.w = a_ld(s + 3);
            lds_h4[bb][c2] = v;
            unsigned* s2 = s + 128;
            uint4 v2;
            v2.x = a_ld(s2); v2.y = a_ld(s2 + 1); v2.z = a_ld(s2 + 2); v2.w = a_ld(s2 + 3);
            lds_h4[bb][c2 + 32] = v2;
        } else if (tid < 320) {
            int v = tid - 256, b = v >> 3, n = v & 7;
            float* base = Pbuf + (size_t)(par * 8 + gid) * 32 * 192 + b * 24 + n * 3;
            float s0 = 0.f, s1 = 0.f, s2 = 0.f;
            #pragma unroll
            for (int k = 0; k < 32; ++k) {
                float* pj = base + k * 192;
                s0 += a_ldf(pj); s1 += a_ldf(pj + 1); s2 += a_ldf(pj + 2);
            }
            s0 *= 0.125f; s1 *= 0.125f; s2 *= 0.125f;
            float mx = fmaxf(s0, fmaxf(s1, s2));
            float e0 = __expf(s0 - mx), e1 = __expf(s1 - mx), e2 = __expf(s2 - mx);
            float inv = 1.f / (e0 + e1 + e2);
            a_all[b][n][0] = e0 * inv; a_all[b][n][1] = e1 * inv; a_all[b][n][2] = e2 * inv;
        }
        __syncthreads();                                   // B3

        // ---- GEMM-gh: all 8 waves, K-chunk w ----
        {
            float ag[12];
            #pragma unroll
            for (int i = 0; i < 12; ++i) ag[i] = 0.f;
            int ch0 = w * 8 + chsub * 4;
            #pragma unroll
            for (int i = 0; i < 4; ++i) {
                int ch = ch0 + i;
                uint4 h0 = lds_h4[bp][ch], h1 = lds_h4[bp + 4][ch];
                #pragma unroll
                for (int j = 0; j < 6; ++j) {
                    uint4 wv = lds_Wh[ch][colsub + 8 * j];
                    ag[j]     = dot4(h0, wv, ag[j]);
                    ag[6 + j] = dot4(h1, wv, ag[6 + j]);
                }
            }
            #pragma unroll
            for (int i = 0; i < 12; ++i) ag[i] += __shfl_xor(ag[i], 32);
            if (chsub == 0) {
                #pragma unroll
                for (int j = 0; j < 6; ++j)
                    redH_pk[w][colsub + 8 * j][bp] = pack2f16(ag[j], ag[6 + j]);
            }
        }
        __syncthreads();                                   // B4

        // ---- combine (64..447): ghsum + gxsum ----
        if (tid >= 64 && tid < 448) {
            int idx = tid - 64;
            int col = idx >> 3, bb = idx & 7;
            int bq = bb & 3, hf = bb >> 2;
            float ghsum = 0.f;
            #pragma unroll
            for (int k = 0; k < 8; ++k) {
                fp16x2 v = __builtin_bit_cast(fp16x2, redH_pk[k][col][bq]);
                ghsum += (float)v[hf];
            }
            float gxsum = 0.f;
            #pragma unroll
            for (int g = 0; g < 3; ++g) {
                int sg = (t + 1 + g) % 3;
                #pragma unroll
                for (int k = 0; k < 8; ++k) {
                    fp16x2 u = __builtin_bit_cast(fp16x2, u_pk[sg][k][col][bq]);
                    gxsum += a_all[bb][k][g] * (float)u[hf];
                }
            }
            ghs[col][bb] = ghsum;
            gxs[col][bb] = gxsum;
        }
        __syncthreads();                                   // B5

        // ---- GRU pointwise: h update, hsl, Hbuf publish ----
        if (tid < 128) {
            int c = tid >> 3, bb = tid & 7;
            float r = fsigmoid(gxs[c][bb] + bxr + ghs[c][bb] + bhr);
            float z = fsigmoid(gxs[16 + c][bb] + bxz + ghs[16 + c][bb] + bhz);
            float n = ftanhf(gxs[32 + c][bb] + bxn + r * (ghs[32 + c][bb] + bhn));
            float hnew = (1.f - z) * n + z * hprev;
            hprev = hnew; pooledv += hnew;
            hsl[bb][c] = hnew;
            float hnext = __shfl_down(hnew, 8);
            if ((c & 1) == 0)
                a_st(&Hbuf[(size_t)par * 16384 + (gid * 8 + bb) * 256 + bid * 8 + (c >> 1)],
                     pack2f16(hnew, hnext));
        }
        __syncthreads();                                   // B6  (hsl visible)

        // ---- pscores(t+1) = h-slice . kappa ; publish under flagH ----
        if (tid < 192) {
            int b = tid / 24, r = tid % 24, n = r / 3, g = r % 3;
            int ks = (t + 3 + g) & 3;    // rows t-1, t, t+1
            float p = 0.f;
            #pragma unroll
            for (int m = 0; m < 16; ++m) {
                fp16x2 kv = __builtin_bit_cast(fp16x2, kap[ks][m][b][n >> 1]);
                p += hsl[b][m] * (float)kv[n & 1];
            }
            a_stf(&Pbuf[((size_t)(((t + 1) & 1) * 8 + gid) * 32 + bid) * 192 + tid], p);
        }
        vmem_fence();
        __syncthreads();                                   // B7
        if (tid == 0) a_st(&flagH[gid * 32 + bid], (unsigned)(t + 1));
    }

    // ======== epilogue: pooled -> relu -> FC1 -> FC2 (flagH SEQ+1 / SEQ+2) ========
    float* stage = (float*)&lds_Wh[0][0];
    if (tid < 128) {
        int c = tid >> 3, bb = tid & 7;
        a_stf(&pooled_g[(gid * 8 + bb) * 512 + bid * 16 + c], fmaxf(pooledv, 0.f));
    }
    vmem_fence();
    __syncthreads();
    if (tid == 0) a_st(&flagH[gid * 32 + bid], (unsigned)(SEQ + 1));
    if (w == 0) {
        bool done = lane >= 32;
        while (!__all(done)) {
            if (!done) done = (a_ld(&flagH[gid * 32 + lane]) >= (unsigned)(SEQ + 1));
            if (!__all(done)) __builtin_amdgcn_s_sleep(1);
        }
    }
    __syncthreads();

    for (int i = tid; i < 8 * 512; i += THREADS) {
        int bb = i >> 9, k = i & 511;
        stage[bb * 512 + k] = a_ldf(&pooled_g[(gid * 8 + bb) * 512 + k]);
    }
    __syncthreads();

    if (tid < 128) {
        int c = tid >> 3, bb = tid & 7;
        int cg = bid * 16 + c;
        const float* pr = stage + bb * 512;
        float acc1 = b1[cg];
        for (int k = 0; k < 512; ++k) acc1 += pr[k] * W1[(size_t)k * 512 + cg];
        a_stf(&fc1_g[(gid * 8 + bb) * 512 + cg], acc1);
    }
    vmem_fence();
    __syncthreads();
    if (tid == 0) a_st(&flagH[gid * 32 + bid], (unsigned)(SEQ + 2));

    if (bid == 0) {
        if (w == 0) {
            bool done = lane >= 32;
            while (!__all(done)) {
                if (!done) done = (a_ld(&flagH[gid * 32 + lane]) >= (unsigned)(SEQ + 2));
                if (!__all(done)) __builtin_amdgcn_s_sleep(1);
            }
        }
        __syncthreads();
        for (int i = tid; i < 8 * 512; i += THREADS) {
            int bb = i >> 9, k = i & 511;
            stage[bb * 512 + k] = a_ldf(&fc1_g[(gid * 8 + bb) * 512 + k]);
        }
        __syncthreads();
        if (tid < 80) {
            int bb = tid / 10, cls = tid - bb * 10;
            const float* fr = stage + bb * 512;
            float a2 = b2[cls];
            for (int k = 0; k < 512; ++k) a2 += fr[k] * W2[k * 10 + cls];
            out[(gid * 8 + bb) * 10 + cls] = a2;
        }
    }
}

extern "C" void kernel_launch(void* const* d_in, const int* in_sizes, int n_in,
                              void* d_out, int out_size, void* d_ws, size_t ws_size,
                              hipStream_t stream) {
    const int*   x   = (const int*)d_in[0];
    const float* emb = (const float*)d_in[1];
    const float* Wq  = (const float*)d_in[2];
    const float* Wx  = (const float*)d_in[3];
    const float* Wh  = (const float*)d_in[4];
    const float* bx  = (const float*)d_in[5];
    const float* bh  = (const float*)d_in[6];
    const float* W1  = (const float*)d_in[7];
    const float* b1  = (const float*)d_in[8];
    const float* W2  = (const float*)d_in[9];
    const float* b2  = (const float*)d_in[10];
    uint4* wsp = (uint4*)d_ws;
    float* outp = (float*)d_out;

    hipLaunchKernelGGL(pack_weights, dim3(896), dim3(256), 0, stream, Wq, Wx, Wh, wsp);
    // zero flagH + Hbuf + Pbuf (deterministic rerun)
    hipMemsetAsync((char*)d_ws + SYNC_OFF, 0, 525312, stream);

    void* args[] = { (void*)&x, (void*)&emb, (void*)&wsp, (void*)&bx, (void*)&bh,
                     (void*)&W1, (void*)&b1, (void*)&W2, (void*)&b2, (void*)&outp };
    hipError_t e = hipLaunchCooperativeKernel((void*)gru_scan, dim3(256), dim3(THREADS),
                                              args, 0, stream);
    if (e != hipSuccess) {
        hipLaunchKernelGGL(gru_scan, dim3(256), dim3(THREADS), 0, stream,
                           x, emb, wsp, bx, bh, W1, b1, W2, b2, outp);
    }
}

// Round 13
// 4037.001 us; speedup vs baseline: 1.5477x; 1.1987x over previous
//
#include <hip/hip_runtime.h>
#include <hip/hip_fp16.h>

typedef __attribute__((ext_vector_type(2))) _Float16 half2v;
typedef __attribute__((ext_vector_type(2))) __fp16   fp16x2;

#define SEQ     512
#define THREADS 512

// ws layout (uint4 units): Wq col-packed [64][512] @0; Wx [64][1536] @32768; Wh @131072
#define WQ_OFF   0
#define WX_OFF   32768
#define WH_OFF   131072
#define SYNC_OFF 3670016
// sync region (bytes): flagH u32[256]@0 ; flagS u32[256]@1024 ;
// Hbuf u32[2][64][256]@2048 (131072) ; Pbuf f32[2][8][32][24]@133120 ;
// pooled f32[64][512]@182272 ; fc1 f32[64][512]@313344

__device__ inline unsigned int pack2f16(float a, float b) {
    fp16x2 p = __builtin_amdgcn_cvt_pkrtz(a, b);
    return __builtin_bit_cast(unsigned int, p);
}
__device__ inline float fdot2u(unsigned int a, unsigned int b, float acc) {
    return __builtin_amdgcn_fdot2(__builtin_bit_cast(half2v, a),
                                  __builtin_bit_cast(half2v, b), acc, false);
}
__device__ inline float dot4(uint4 h, uint4 w, float acc) {
    acc = fdot2u(h.x, w.x, acc); acc = fdot2u(h.y, w.y, acc);
    acc = fdot2u(h.z, w.z, acc); acc = fdot2u(h.w, w.w, acc);
    return acc;
}
__device__ inline float fsigmoid(float x) { return 1.f / (1.f + __expf(-x)); }
__device__ inline float ftanhf(float x) {
    float e = __expf(-2.f * fabsf(x));
    float t = (1.f - e) / (1.f + e);
    return copysignf(t, x);
}
__device__ inline void vmem_fence() { asm volatile("s_waitcnt vmcnt(0)" ::: "memory"); }
__device__ inline unsigned a_ld(unsigned* p) {
    return __hip_atomic_load(p, __ATOMIC_RELAXED, __HIP_MEMORY_SCOPE_AGENT);
}
__device__ inline void a_st(unsigned* p, unsigned v) {
    __hip_atomic_store(p, v, __ATOMIC_RELAXED, __HIP_MEMORY_SCOPE_AGENT);
}
__device__ inline float a_ldf(float* p) {
    return __hip_atomic_load(p, __ATOMIC_RELAXED, __HIP_MEMORY_SCOPE_AGENT);
}
__device__ inline void a_stf(float* p, float v) {
    __hip_atomic_store(p, v, __ATOMIC_RELAXED, __HIP_MEMORY_SCOPE_AGENT);
}

__global__ __launch_bounds__(256)
void pack_weights(const float* __restrict__ Wq,
                  const float* __restrict__ Wx,
                  const float* __restrict__ Wh,
                  uint4* __restrict__ ws) {
    int tid = blockIdx.x * blockDim.x + threadIdx.x;  // 0 .. 229375
    const float* src; uint4* dst; int C, idx;
    if (tid < 64 * 512)                  { src = Wq; dst = ws;          C = 512;  idx = tid; }
    else if (tid < 64 * 512 + 64 * 1536) { src = Wx; dst = ws + WX_OFF; C = 1536; idx = tid - 64 * 512; }
    else                                 { src = Wh; dst = ws + WH_OFF; C = 1536; idx = tid - (64 * 512 + 64 * 1536); }
    int m4 = idx / C;
    int c  = idx - m4 * C;
    const float* s = src + (size_t)(m4 * 8) * C + c;
    uint4 o;
    o.x = pack2f16(s[0 * (size_t)C], s[1 * (size_t)C]);
    o.y = pack2f16(s[2 * (size_t)C], s[3 * (size_t)C]);
    o.z = pack2f16(s[4 * (size_t)C], s[5 * (size_t)C]);
    o.w = pack2f16(s[6 * (size_t)C], s[7 * (size_t)C]);
    dst[idx] = o;
}

// 256 blocks. gid = blk & 7 (XCD-local groups), bid = blk >> 3. Group owns batches
// 8*gid..+8; block owns q-cols/gate-cols [bid*16,+16). Two syncs/step (h, pscores).
// Wave0: no prefetch duty; owns score chain + pointwise + barrier-free h publish.
__global__ __launch_bounds__(THREADS)
void gru_scan(const int* __restrict__ xtok, const float* __restrict__ emb,
              const uint4* __restrict__ wsp, const float* __restrict__ bx,
              const float* __restrict__ bh, const float* __restrict__ W1,
              const float* __restrict__ b1, const float* __restrict__ W2,
              const float* __restrict__ b2, float* __restrict__ out)
{
    const int blk  = blockIdx.x;
    const int gid  = blk & 7;
    const int bid  = blk >> 3;
    const int tid  = threadIdx.x;
    const int lane = tid & 63;
    const int w    = tid >> 6;
    const int colsub = lane & 7;
    const int bp     = (lane >> 3) & 3;
    const int chsub  = lane >> 5;

    char* syncb = (char*)wsp + SYNC_OFF;
    unsigned* flagH = (unsigned*)syncb;
    unsigned* flagS = (unsigned*)(syncb + 1024);
    unsigned* Hbuf  = (unsigned*)(syncb + 2048);
    float* Pbuf     = (float*)(syncb + 133120);
    float* pooled_g = (float*)(syncb + 182272);
    float* fc1_g    = (float*)(syncb + 313344);

    __shared__ uint4 lds_W [64][65];       // cols 0..15 Wq-slice, 16..63 Wh-slice
    __shared__ uint4 lds_Wx[64][49];       // 48 Wx cols
    __shared__ uint4 lds_h4[8][65];        // dual-use: win row t (pre-B0) / h(t-1)
    __shared__ unsigned u_pk[3][8][48][4]; // win@Wx per-head partials, f16 (b, b+4)
    __shared__ float redH[8][48][9];       // gh partials f32
    __shared__ float redC[768];            // combine out: ghs [0..383], gxs [384..767]
    __shared__ float redQsum[144];         // q summed over k: [d][b]
    __shared__ float a_all[8][8][3];

    // ---- persistent weight slices -> LDS ----
    for (int i = tid; i < 64 * 64; i += THREADS) {
        int ch = i >> 6, cl = i & 63;
        uint4 v;
        if (cl < 16) v = wsp[WQ_OFF + ch * 512 + bid * 16 + cl];
        else { int g = (cl - 16) >> 4, c = (cl - 16) & 15;
               v = wsp[WH_OFF + ch * 1536 + g * 512 + bid * 16 + c]; }
        lds_W[ch][cl] = v;
    }
    for (int i = tid; i < 64 * 48; i += THREADS) {
        int ch = i / 48, cl = i - ch * 48;
        int g = cl >> 4, c = cl & 15;
        lds_Wx[ch][cl] = wsp[WX_OFF + ch * 1536 + g * 512 + bid * 16 + c];
    }

    // wave0 biases: lane owns cols 2cp, 2cp+1 (cp = lane&7) for batch bb = lane>>3
    float bhr0 = 0, bhr1 = 0, bhz0 = 0, bhz1 = 0, bhn0 = 0, bhn1 = 0;
    float bxr0 = 0, bxr1 = 0, bxz0 = 0, bxz1 = 0, bxn0 = 0, bxn1 = 0;
    if (w == 0) {
        int cg = bid * 16 + (lane & 7) * 2;
        bhr0 = bh[cg];        bhr1 = bh[cg + 1];
        bhz0 = bh[512 + cg];  bhz1 = bh[513 + cg];
        bhn0 = bh[1024 + cg]; bhn1 = bh[1025 + cg];
        bxr0 = bx[cg];        bxr1 = bx[cg + 1];
        bxz0 = bx[512 + cg];  bxz1 = bx[513 + cg];
        bxn0 = bx[1024 + cg]; bxn1 = bx[1025 + cg];
    }

    // ---- pre-loop: duty waves (w>=1; wave1 also batch 0) stage win row 0 ----
    if (w >= 1) {
        #pragma unroll 1
        for (int rep = 0; rep < 2; ++rep) {
            if (rep == 1 && w != 1) break;
            int bd = (rep == 0) ? w : 0;
            int tk = xtok[(gid * 8 + bd) * SEQ];
            const float4* p = (const float4*)(emb + (size_t)tk * 512 + lane * 8);
            float4 ra = p[0], rb = p[1];
            uint4 pk;
            pk.x = pack2f16(ra.x, ra.y); pk.y = pack2f16(ra.z, ra.w);
            pk.z = pack2f16(rb.x, rb.y); pk.w = pack2f16(rb.z, rb.w);
            lds_h4[bd][lane] = pk;
        }
    }
    {
        unsigned* up = &u_pk[0][0][0][0];
        for (int i = tid; i < 3072; i += THREADS) up[1536 + i] = 0u;  // u slots 1,2 = 0
    }
    float hp0 = 0.f, hp1 = 0.f, pv0 = 0.f, pv1 = 0.f;   // wave0 state (2 per lane)
    __syncthreads();

    for (int t = 0; t < SEQ; ++t) {
        const int par   = t & 1;
        const int uslot = t % 3;

        // ---- prefetch win row t+1 (duty waves only) ----
        float4 r3a0, r3b0, r3a1, r3b1;
        if (w >= 1) {
            int tn = (t + 1 < SEQ) ? t + 1 : t;
            int tk = xtok[(gid * 8 + w) * SEQ + tn];
            const float4* pn = (const float4*)(emb + (size_t)tk * 512 + lane * 8);
            r3a0 = pn[0]; r3b0 = pn[1];
            if (w == 1) {
                int tk0 = xtok[(gid * 8 + 0) * SEQ + tn];
                const float4* p0 = (const float4*)(emb + (size_t)tk0 * 512 + lane * 8);
                r3a1 = p0[0]; r3b1 = p0[1];
            }
        }

        // ---- wave0: winv slices for scores ----
        float winv[16];
        int b3 = 0, g3 = 0, trow = -1;
        if (w == 0 && lane < 24) {
            b3 = lane / 3; g3 = lane - b3 * 3;
            trow = t - 2 + g3;
            int tok = (trow >= 0) ? xtok[(gid * 8 + b3) * SEQ + trow] : -1;
            if (tok >= 0) {
                const float* er = emb + (size_t)tok * 512 + bid * 16;
                #pragma unroll
                for (int d = 0; d < 16; ++d) winv[d] = er[d];
            } else {
                #pragma unroll
                for (int d = 0; d < 16; ++d) winv[d] = 0.f;
            }
        }

        // ---- wave0 polls flagH | waves1-7: U(row t) (wave7 also k=0) ----
        if (w == 0) {
            bool done = lane >= 32;
            while (!__all(done)) {
                if (!done) done = (a_ld(&flagH[gid * 32 + lane]) >= (unsigned)t);
                if (!__all(done)) __builtin_amdgcn_s_sleep(1);
            }
        } else {
            #pragma unroll 1
            for (int rep = 0; rep < 2; ++rep) {
                int k = (rep == 0) ? w : 0;
                if (rep == 1 && w != 7) break;
                float acu[12];
                #pragma unroll
                for (int i = 0; i < 12; ++i) acu[i] = 0.f;
                int ch0 = k * 8 + chsub * 4;
                #pragma unroll
                for (int i = 0; i < 4; ++i) {
                    int ch = ch0 + i;
                    uint4 c0 = lds_h4[bp][ch], c1 = lds_h4[bp + 4][ch];
                    #pragma unroll
                    for (int j = 0; j < 6; ++j) {
                        uint4 wv = lds_Wx[ch][colsub + 8 * j];
                        acu[j]     = dot4(c0, wv, acu[j]);
                        acu[6 + j] = dot4(c1, wv, acu[6 + j]);
                    }
                }
                #pragma unroll
                for (int i = 0; i < 12; ++i) acu[i] += __shfl_xor(acu[i], 32);
                if (chsub == 0) {
                    #pragma unroll
                    for (int j = 0; j < 6; ++j)
                        u_pk[uslot][k][colsub + 8 * j][bp] = pack2f16(acu[j], acu[6 + j]);
                }
            }
        }
        __syncthreads();                                   // B0

        // ---- h-load (all threads, 1 uint4) + zero redQsum ----
        {
            int bb = tid >> 6, ch = tid & 63;
            unsigned* s = Hbuf + (size_t)(par ^ 1) * 16384 + (gid * 8 + bb) * 256 + ch * 4;
            uint4 v;
            v.x = a_ld(s); v.y = a_ld(s + 1); v.z = a_ld(s + 2); v.w = a_ld(s + 3);
            lds_h4[bb][ch] = v;
        }
        if (tid < 144) redQsum[tid] = 0.f;
        __syncthreads();                                   // B2

        // ---- GEMM-q (all 8 waves, k=w) -> atomicAdd into redQsum ----
        {
            float aq0 = 0, aq1 = 0, aq2 = 0, aq3 = 0;
            int ch0 = w * 8 + chsub * 4;
            #pragma unroll
            for (int i = 0; i < 4; ++i) {
                int ch = ch0 + i;
                uint4 h0 = lds_h4[bp][ch], h1 = lds_h4[bp + 4][ch];
                uint4 w0 = lds_W[ch][colsub], w1 = lds_W[ch][colsub + 8];
                aq0 = dot4(h0, w0, aq0); aq1 = dot4(h0, w1, aq1);
                aq2 = dot4(h1, w0, aq2); aq3 = dot4(h1, w1, aq3);
            }
            aq0 += __shfl_xor(aq0, 32); aq1 += __shfl_xor(aq1, 32);
            aq2 += __shfl_xor(aq2, 32); aq3 += __shfl_xor(aq3, 32);
            if (chsub == 0) {
                atomicAdd(&redQsum[colsub * 9 + bp], aq0);
                atomicAdd(&redQsum[(colsub + 8) * 9 + bp], aq1);
                atomicAdd(&redQsum[colsub * 9 + bp + 4], aq2);
                atomicAdd(&redQsum[(colsub + 8) * 9 + bp + 4], aq3);
            }
        }
        __syncthreads();                                   // B3

        // ---- wave0: score chain | waves1-7: GEMM-gh (wave7 also k=0) ----
        if (w == 0) {
            if (lane < 24) {
                float s = 0.f;
                if (trow >= 0) {
                    #pragma unroll
                    for (int d = 0; d < 16; ++d) s += winv[d] * redQsum[d * 9 + b3];
                }
                a_stf(&Pbuf[(size_t)((par * 8 + gid) * 32 + bid) * 24 + b3 * 3 + g3], s);
            }
            vmem_fence();                                  // wave0: only own stores pending
            if (lane == 0) a_st(&flagS[gid * 32 + bid], (unsigned)(t + 1));
            bool done = lane >= 32;
            while (!__all(done)) {
                if (!done) done = (a_ld(&flagS[gid * 32 + lane]) >= (unsigned)(t + 1));
                if (!__all(done)) __builtin_amdgcn_s_sleep(1);
            }
            {
                int bb = lane >> 3, n = lane & 7;
                float* pb = Pbuf + (size_t)(par * 8 + gid) * 32 * 24;
                float sc0 = 0, sc1 = 0, sc2 = 0;
                #pragma unroll
                for (int j = 0; j < 4; ++j) {
                    float* pj = pb + (n * 4 + j) * 24 + bb * 3;
                    sc0 += a_ldf(pj); sc1 += a_ldf(pj + 1); sc2 += a_ldf(pj + 2);
                }
                sc0 *= 0.125f; sc1 *= 0.125f; sc2 *= 0.125f;
                float mx = fmaxf(sc0, fmaxf(sc1, sc2));
                float e0 = __expf(sc0 - mx), e1 = __expf(sc1 - mx), e2 = __expf(sc2 - mx);
                float inv = 1.f / (e0 + e1 + e2);
                a_all[bb][n][0] = e0 * inv; a_all[bb][n][1] = e1 * inv; a_all[bb][n][2] = e2 * inv;
            }
        } else {
            #pragma unroll 1
            for (int rep = 0; rep < 2; ++rep) {
                int k = (rep == 0) ? w : 0;
                if (rep == 1 && w != 7) break;
                float ag[12];
                #pragma unroll
                for (int i = 0; i < 12; ++i) ag[i] = 0.f;
                int ch0 = k * 8 + chsub * 4;
                #pragma unroll
                for (int i = 0; i < 4; ++i) {
                    int ch = ch0 + i;
                    uint4 h0 = lds_h4[bp][ch], h1 = lds_h4[bp + 4][ch];
                    #pragma unroll
                    for (int j = 0; j < 6; ++j) {
                        uint4 wv = lds_W[ch][16 + colsub + 8 * j];
                        ag[j]     = dot4(h0, wv, ag[j]);
                        ag[6 + j] = dot4(h1, wv, ag[6 + j]);
                    }
                }
                #pragma unroll
                for (int i = 0; i < 12; ++i) ag[i] += __shfl_xor(ag[i], 32);
                if (chsub == 0) {
                    #pragma unroll
                    for (int j = 0; j < 6; ++j) {
                        redH[k][colsub + 8 * j][bp]     = ag[j];
                        redH[k][colsub + 8 * j][bp + 4] = ag[6 + j];
                    }
                }
            }
        }
        __syncthreads();                                   // B4

        // ---- combine (tid 64..447) + win-pack (duty waves) ----
        if (tid >= 64 && tid < 448) {
            int idx = tid - 64;
            int col = idx >> 3, bb = idx & 7;
            float ghsum = redH[0][col][bb];
            #pragma unroll
            for (int k = 1; k < 8; ++k) ghsum += redH[k][col][bb];
            float gxsum = 0.f;
            int half = bb >> 2, bq = bb & 3;
            #pragma unroll
            for (int g = 0; g < 3; ++g) {
                int sg = (t + 1 + g) % 3;
                #pragma unroll
                for (int k = 0; k < 8; ++k) {
                    fp16x2 uv = __builtin_bit_cast(fp16x2, u_pk[sg][k][col][bq]);
                    gxsum += a_all[bb][k][g] * (float)uv[half];
                }
            }
            redC[col * 8 + bb]       = ghsum;
            redC[384 + col * 8 + bb] = gxsum;
        }
        if (w >= 1) {
            uint4 pk;
            pk.x = pack2f16(r3a0.x, r3a0.y); pk.y = pack2f16(r3a0.z, r3a0.w);
            pk.z = pack2f16(r3b0.x, r3b0.y); pk.w = pack2f16(r3b0.z, r3b0.w);
            lds_h4[w][lane] = pk;
            if (w == 1) {
                uint4 pk1;
                pk1.x = pack2f16(r3a1.x, r3a1.y); pk1.y = pack2f16(r3a1.z, r3a1.w);
                pk1.z = pack2f16(r3b1.x, r3b1.y); pk1.w = pack2f16(r3b1.z, r3b1.w);
                lds_h4[0][lane] = pk1;
            }
        }
        __syncthreads();                                   // B5

        // ---- wave0 ONLY: pointwise x2, publish h + flagH (NO barrier after) ----
        if (w == 0) {
            int bb = lane >> 3, cp = lane & 7;
            int c0 = cp * 2, c1 = c0 + 1;
            float r0 = fsigmoid(redC[384 + c0 * 8 + bb] + bxr0 + redC[c0 * 8 + bb] + bhr0);
            float z0 = fsigmoid(redC[384 + (16 + c0) * 8 + bb] + bxz0 + redC[(16 + c0) * 8 + bb] + bhz0);
            float n0 = ftanhf(redC[384 + (32 + c0) * 8 + bb] + bxn0 + r0 * (redC[(32 + c0) * 8 + bb] + bhn0));
            float h0 = (1.f - z0) * n0 + z0 * hp0;
            float r1 = fsigmoid(redC[384 + c1 * 8 + bb] + bxr1 + redC[c1 * 8 + bb] + bhr1);
            float z1 = fsigmoid(redC[384 + (16 + c1) * 8 + bb] + bxz1 + redC[(16 + c1) * 8 + bb] + bhz1);
            float n1 = ftanhf(redC[384 + (32 + c1) * 8 + bb] + bxn1 + r1 * (redC[(32 + c1) * 8 + bb] + bhn1));
            float h1 = (1.f - z1) * n1 + z1 * hp1;
            hp0 = h0; hp1 = h1; pv0 += h0; pv1 += h1;
            a_st(&Hbuf[(size_t)par * 16384 + (gid * 8 + bb) * 256 + bid * 8 + cp],
                 pack2f16(h0, h1));
            vmem_fence();                                  // own stores only
            if (lane == 0) a_st(&flagH[gid * 32 + bid], (unsigned)(t + 1));
        }
        // waves 1-7 proceed directly to next iteration (prefetch + U overlap wave0)
    }

    // ======== epilogue: pooled -> relu -> FC1 -> FC2 ========
    float* stage = (float*)&lds_W[0][0];
    if (w == 0) {
        int bb = lane >> 3, cp = lane & 7;
        a_stf(&pooled_g[(gid * 8 + bb) * 512 + bid * 16 + cp * 2],     fmaxf(pv0, 0.f));
        a_stf(&pooled_g[(gid * 8 + bb) * 512 + bid * 16 + cp * 2 + 1], fmaxf(pv1, 0.f));
        vmem_fence();
    }
    __syncthreads();
    if (tid == 0) a_st(&flagS[gid * 32 + bid], (unsigned)(SEQ + 1));
    if (w == 0) {
        bool done = lane >= 32;
        while (!__all(done)) {
            if (!done) done = (a_ld(&flagS[gid * 32 + lane]) >= (unsigned)(SEQ + 1));
            if (!__all(done)) __builtin_amdgcn_s_sleep(1);
        }
    }
    __syncthreads();

    for (int i = tid; i < 8 * 512; i += THREADS) {
        int bb = i >> 9, k = i & 511;
        stage[bb * 512 + k] = a_ldf(&pooled_g[(gid * 8 + bb) * 512 + k]);
    }
    __syncthreads();

    if (tid < 128) {
        int c = tid >> 3, bb = tid & 7;
        int cg = bid * 16 + c;
        const float* pr = stage + bb * 512;
        float acc1 = b1[cg];
        for (int k = 0; k < 512; ++k) acc1 += pr[k] * W1[(size_t)k * 512 + cg];
        a_stf(&fc1_g[(gid * 8 + bb) * 512 + cg], acc1);
    }
    vmem_fence();
    __syncthreads();
    if (tid == 0) a_st(&flagH[gid * 32 + bid], (unsigned)(SEQ + 2));

    if (bid == 0) {
        if (w == 0) {
            bool done = lane >= 32;
            while (!__all(done)) {
                if (!done) done = (a_ld(&flagH[gid * 32 + lane]) >= (unsigned)(SEQ + 2));
                if (!__all(done)) __builtin_amdgcn_s_sleep(1);
            }
        }
        __syncthreads();
        for (int i = tid; i < 8 * 512; i += THREADS) {
            int bb = i >> 9, k = i & 511;
            stage[bb * 512 + k] = a_ldf(&fc1_g[(gid * 8 + bb) * 512 + k]);
        }
        __syncthreads();
        if (tid < 80) {
            int bb = tid / 10, cls = tid - bb * 10;
            const float* fr = stage + bb * 512;
            float a2 = b2[cls];
            for (int k = 0; k < 512; ++k) a2 += fr[k] * W2[k * 10 + cls];
            out[(gid * 8 + bb) * 10 + cls] = a2;
        }
    }
}

extern "C" void kernel_launch(void* const* d_in, const int* in_sizes, int n_in,
                              void* d_out, int out_size, void* d_ws, size_t ws_size,
                              hipStream_t stream) {
    const int*   x   = (const int*)d_in[0];
    const float* emb = (const float*)d_in[1];
    const float* Wq  = (const float*)d_in[2];
    const float* Wx  = (const float*)d_in[3];
    const float* Wh  = (const float*)d_in[4];
    const float* bx  = (const float*)d_in[5];
    const float* bh  = (const float*)d_in[6];
    const float* W1  = (const float*)d_in[7];
    const float* b1  = (const float*)d_in[8];
    const float* W2  = (const float*)d_in[9];
    const float* b2  = (const float*)d_in[10];
    uint4* wsp = (uint4*)d_ws;
    float* outp = (float*)d_out;

    hipLaunchKernelGGL(pack_weights, dim3(896), dim3(256), 0, stream, Wq, Wx, Wh, wsp);
    hipMemsetAsync((char*)d_ws + SYNC_OFF, 0, 182272, stream);

    void* args[] = { (void*)&x, (void*)&emb, (void*)&wsp, (void*)&bx, (void*)&bh,
                     (void*)&W1, (void*)&b1, (void*)&W2, (void*)&b2, (void*)&outp };
    hipError_t e = hipLaunchCooperativeKernel((void*)gru_scan, dim3(256), dim3(THREADS),
                                              args, 0, stream);
    if (e != hipSuccess) {
        hipLaunchKernelGGL(gru_scan, dim3(256), dim3(THREADS), 0, stream,
                           x, emb, wsp, bx, bh, W1, b1, W2, b2, outp);
    }
}

// Round 15
// 3589.314 us; speedup vs baseline: 1.7407x; 1.1247x over previous
//
#include <hip/hip_runtime.h>
#include <hip/hip_fp16.h>

typedef __attribute__((ext_vector_type(2))) _Float16 half2v;
typedef __attribute__((ext_vector_type(2))) __fp16   fp16x2;

#define SEQ     512
#define THREADS 512

// ws layout (uint4 units): Wq col-packed [64][512] @0; Wx [64][1536] @32768; Wh @131072
#define WQ_OFF   0
#define WX_OFF   32768
#define WH_OFF   131072
#define SYNC_OFF 3670016
// sync region (bytes): flagH u32[256]@0 ; flagS u32[256]@1024 ;
// Hbuf u32[2][64][256]@2048 (131072) ; Pbuf f32[2][8][32][24]@133120 ;
// pooled f32[64][512]@182272 ; fc1 f32[64][512]@313344

__device__ inline unsigned int pack2f16(float a, float b) {
    fp16x2 p = __builtin_amdgcn_cvt_pkrtz(a, b);
    return __builtin_bit_cast(unsigned int, p);
}
__device__ inline float fdot2u(unsigned int a, unsigned int b, float acc) {
    return __builtin_amdgcn_fdot2(__builtin_bit_cast(half2v, a),
                                  __builtin_bit_cast(half2v, b), acc, false);
}
__device__ inline float dot4(uint4 h, uint4 w, float acc) {
    acc = fdot2u(h.x, w.x, acc); acc = fdot2u(h.y, w.y, acc);
    acc = fdot2u(h.z, w.z, acc); acc = fdot2u(h.w, w.w, acc);
    return acc;
}
__device__ inline float fsigmoid(float x) { return 1.f / (1.f + __expf(-x)); }
__device__ inline float ftanhf(float x) {
    float e = __expf(-2.f * fabsf(x));
    float t = (1.f - e) / (1.f + e);
    return copysignf(t, x);
}
__device__ inline void vmem_fence() { asm volatile("s_waitcnt vmcnt(0)" ::: "memory"); }
__device__ inline unsigned a_ld(unsigned* p) {
    return __hip_atomic_load(p, __ATOMIC_RELAXED, __HIP_MEMORY_SCOPE_AGENT);
}
__device__ inline void a_st(unsigned* p, unsigned v) {
    __hip_atomic_store(p, v, __ATOMIC_RELAXED, __HIP_MEMORY_SCOPE_AGENT);
}
__device__ inline float a_ldf(float* p) {
    return __hip_atomic_load(p, __ATOMIC_RELAXED, __HIP_MEMORY_SCOPE_AGENT);
}
__device__ inline void a_stf(float* p, float v) {
    __hip_atomic_store(p, v, __ATOMIC_RELAXED, __HIP_MEMORY_SCOPE_AGENT);
}

__global__ __launch_bounds__(256)
void pack_weights(const float* __restrict__ Wq,
                  const float* __restrict__ Wx,
                  const float* __restrict__ Wh,
                  uint4* __restrict__ ws) {
    int tid = blockIdx.x * blockDim.x + threadIdx.x;  // 0 .. 229375
    const float* src; uint4* dst; int C, idx;
    if (tid < 64 * 512)                  { src = Wq; dst = ws;          C = 512;  idx = tid; }
    else if (tid < 64 * 512 + 64 * 1536) { src = Wx; dst = ws + WX_OFF; C = 1536; idx = tid - 64 * 512; }
    else                                 { src = Wh; dst = ws + WH_OFF; C = 1536; idx = tid - (64 * 512 + 64 * 1536); }
    int m4 = idx / C;
    int c  = idx - m4 * C;
    const float* s = src + (size_t)(m4 * 8) * C + c;
    uint4 o;
    o.x = pack2f16(s[0 * (size_t)C], s[1 * (size_t)C]);
    o.y = pack2f16(s[2 * (size_t)C], s[3 * (size_t)C]);
    o.z = pack2f16(s[4 * (size_t)C], s[5 * (size_t)C]);
    o.w = pack2f16(s[6 * (size_t)C], s[7 * (size_t)C]);
    dst[idx] = o;
}

// 256 blocks. gid = blk & 7 (XCD-local groups), bid = blk >> 3. Group owns batches
// 8*gid..+8; block owns q-cols [bid*16,+16), gate cols [bid*16,+16) per gate.
// GEMM-gx replaced by h-independent per-head window GEMM (u_pk, 3-slot rolling).
__global__ __launch_bounds__(THREADS)
void gru_scan(const int* __restrict__ xtok, const float* __restrict__ emb,
              const uint4* __restrict__ wsp, const float* __restrict__ bx,
              const float* __restrict__ bh, const float* __restrict__ W1,
              const float* __restrict__ b1, const float* __restrict__ W2,
              const float* __restrict__ b2, float* __restrict__ out)
{
    const int blk  = blockIdx.x;
    const int gid  = blk & 7;
    const int bid  = blk >> 3;
    const int tid  = threadIdx.x;
    const int lane = tid & 63;
    const int wid  = tid >> 6;
    const int colsub = lane & 7;
    const int bp     = (lane >> 3) & 3;
    const int chsub  = lane >> 5;

    char* syncb = (char*)wsp + SYNC_OFF;
    unsigned* flagH = (unsigned*)syncb;
    unsigned* flagS = (unsigned*)(syncb + 1024);
    unsigned* Hbuf  = (unsigned*)(syncb + 2048);
    float* Pbuf     = (float*)(syncb + 133120);
    float* pooled_g = (float*)(syncb + 182272);
    float* fc1_g    = (float*)(syncb + 313344);

    __shared__ uint4 lds_W [64][65];       // cols 0..15 Wq-slice, 16..63 Wh-slice
    __shared__ uint4 lds_Wx[64][49];       // 48 Wx cols
    __shared__ uint4 lds_h4[8][65];        // dual-use: win row t (pre-B0) / h(t-1)
    __shared__ unsigned u_pk[3][8][48][4]; // per-head win@Wx partials, f16 pairs (b, b+4)
    __shared__ float redQf[1152];          // GEMM-q partials; then ghsum/gxsum
    __shared__ float redH[8][48][9];       // GEMM-gh partials (per head chunk)
    __shared__ float a_all[8][8][3];

    // ---- persistent weight slices -> LDS ----
    for (int i = tid; i < 64 * 64; i += THREADS) {
        int ch = i >> 6, cl = i & 63;
        uint4 v;
        if (cl < 16) v = wsp[WQ_OFF + ch * 512 + bid * 16 + cl];
        else { int g = (cl - 16) >> 4, c = (cl - 16) & 15;
               v = wsp[WH_OFF + ch * 1536 + g * 512 + bid * 16 + c]; }
        lds_W[ch][cl] = v;
    }
    for (int i = tid; i < 64 * 48; i += THREADS) {
        int ch = i / 48, cl = i - ch * 48;
        int g = cl >> 4, c = cl & 15;
        lds_Wx[ch][cl] = wsp[WX_OFF + ch * 1536 + g * 512 + bid * 16 + c];
    }

    float bxr = 0, bxz = 0, bxn = 0, bhr = 0, bhz = 0, bhn = 0;
    if (tid < 128) {
        int c = tid >> 3, cg = bid * 16 + c;
        bxr = bx[cg]; bxz = bx[512 + cg]; bxn = bx[1024 + cg];
        bhr = bh[cg]; bhz = bh[512 + cg]; bhn = bh[1024 + cg];
    }

    const int gb = gid * 8 + wid;
    // pre-loop: win row 0 -> lds_h4 ; zero u slots 1,2 (rows -2,-1)
    {
        int tk = xtok[gb * SEQ];
        const float4* p = (const float4*)(emb + (size_t)tk * 512 + lane * 8);
        float4 ra = p[0], rb = p[1];
        uint4 pk;
        pk.x = pack2f16(ra.x, ra.y); pk.y = pack2f16(ra.z, ra.w);
        pk.z = pack2f16(rb.x, rb.y); pk.w = pack2f16(rb.z, rb.w);
        lds_h4[wid][lane] = pk;
        unsigned* up = &u_pk[0][0][0][0];
        for (int i = tid; i < 3072; i += THREADS) up[1536 + i] = 0u;
    }
    float hprev = 0.f, pooledv = 0.f;
    __syncthreads();

    for (int t = 0; t < SEQ; ++t) {
        const int par = t & 1;
        const int slot = t % 3;

        // ---- prefetch win row t+1 (regs) + winv slices for scores ----
        int tnext = (t + 1 < SEQ) ? (t + 1) : t;
        int tkn = xtok[gb * SEQ + tnext];
        const float4* pn = (const float4*)(emb + (size_t)tkn * 512 + lane * 8);
        float4 r3a = pn[0], r3b = pn[1];

        float winv[16];
        int b3 = 0, g3 = 0, trow = -1;
        if (wid == 0 && lane < 24) {
            b3 = lane / 3; g3 = lane - b3 * 3;
            trow = t - 2 + g3;
            int tok = (trow >= 0) ? xtok[(gid * 8 + b3) * SEQ + trow] : -1;
            if (tok >= 0) {
                const float* er = emb + (size_t)tok * 512 + bid * 16;
                #pragma unroll
                for (int d = 0; d < 16; ++d) winv[d] = er[d];
            } else {
                #pragma unroll
                for (int d = 0; d < 16; ++d) winv[d] = 0.f;
            }
        }

        // ---- Phase U: u_pk[slot] = (win row t) @ Wx, per-head partials ----
        {
            float acu[12];
            #pragma unroll
            for (int i = 0; i < 12; ++i) acu[i] = 0.f;
            int ch0 = wid * 8 + chsub * 4;
            #pragma unroll
            for (int i = 0; i < 4; ++i) {
                int ch = ch0 + i;
                uint4 c0 = lds_h4[bp][ch], c1 = lds_h4[bp + 4][ch];
                #pragma unroll
                for (int j = 0; j < 6; ++j) {
                    uint4 w = lds_Wx[ch][colsub + 8 * j];
                    acu[j]     = dot4(c0, w, acu[j]);
                    acu[6 + j] = dot4(c1, w, acu[6 + j]);
                }
            }
            #pragma unroll
            for (int i = 0; i < 12; ++i) acu[i] += __shfl_xor(acu[i], 32);
            if (chsub == 0) {
                #pragma unroll
                for (int j = 0; j < 6; ++j)
                    u_pk[slot][wid][colsub + 8 * j][bp] = pack2f16(acu[j], acu[6 + j]);
            }
        }

        // ---- wave0: wait h(t-1) from all 32 blocks ----
        if (wid == 0) {
            bool done = lane >= 32;
            while (!__all(done)) {
                if (!done) done = (a_ld(&flagH[gid * 32 + lane]) >= (unsigned)t);
                if (!__all(done)) __builtin_amdgcn_s_sleep(1);
            }
        }
        __syncthreads();                                   // B0

        // ---- load h(t-1) -> lds_h4 (overwrites win; U done reading) ----
        {
            int bb = tid >> 6, c4 = tid & 63;
            unsigned* s = Hbuf + (size_t)(par ^ 1) * 16384 + (gid * 8 + bb) * 256 + c4 * 4;
            uint4 v;
            v.x = a_ld(s); v.y = a_ld(s + 1); v.z = a_ld(s + 2); v.w = a_ld(s + 3);
            lds_h4[bb][c4] = v;
        }
        __syncthreads();                                   // B2

        // ---- GEMM-q (16 cols) ----
        {
            float aq0 = 0, aq1 = 0, aq2 = 0, aq3 = 0;
            int ch0 = wid * 8 + chsub * 4;
            #pragma unroll
            for (int i = 0; i < 4; ++i) {
                int ch = ch0 + i;
                uint4 h0 = lds_h4[bp][ch], h1 = lds_h4[bp + 4][ch];
                uint4 w0 = lds_W[ch][colsub], w1 = lds_W[ch][colsub + 8];
                aq0 = dot4(h0, w0, aq0); aq1 = dot4(h0, w1, aq1);
                aq2 = dot4(h1, w0, aq2); aq3 = dot4(h1, w1, aq3);
            }
            aq0 += __shfl_xor(aq0, 32); aq1 += __shfl_xor(aq1, 32);
            aq2 += __shfl_xor(aq2, 32); aq3 += __shfl_xor(aq3, 32);
            if (chsub == 0) {
                redQf[(wid * 16 + colsub) * 9 + bp]         = aq0;
                redQf[(wid * 16 + colsub + 8) * 9 + bp]     = aq1;
                redQf[(wid * 16 + colsub) * 9 + bp + 4]     = aq2;
                redQf[(wid * 16 + colsub + 8) * 9 + bp + 4] = aq3;
            }
        }
        __syncthreads();                                   // B3

        // ---- wave0: score chain | waves1-7: GEMM-gh (wave7 also head 0) ----
        if (wid == 0) {
            if (lane < 24) {
                float s = 0.f;
                if (trow >= 0) {
                    #pragma unroll
                    for (int d = 0; d < 16; ++d) {
                        float q = redQf[d * 9 + b3];
                        #pragma unroll
                        for (int k = 1; k < 8; ++k) q += redQf[(k * 16 + d) * 9 + b3];
                        s += winv[d] * q;
                    }
                }
                a_stf(&Pbuf[(size_t)((par * 8 + gid) * 32 + bid) * 24 + b3 * 3 + g3], s);
            }
            vmem_fence();
            if (lane == 0) a_st(&flagS[gid * 32 + bid], (unsigned)(t + 1));
            bool done = lane >= 32;
            while (!__all(done)) {
                if (!done) done = (a_ld(&flagS[gid * 32 + lane]) >= (unsigned)(t + 1));
                if (!__all(done)) __builtin_amdgcn_s_sleep(1);
            }
            {
                int bb = lane >> 3, n = lane & 7;
                float* pb = Pbuf + (size_t)(par * 8 + gid) * 32 * 24;
                float sc0 = 0, sc1 = 0, sc2 = 0;
                #pragma unroll
                for (int j = 0; j < 4; ++j) {
                    float* pj = pb + (n * 4 + j) * 24 + bb * 3;
                    sc0 += a_ldf(pj); sc1 += a_ldf(pj + 1); sc2 += a_ldf(pj + 2);
                }
                sc0 *= 0.125f; sc1 *= 0.125f; sc2 *= 0.125f;
                float mx = fmaxf(sc0, fmaxf(sc1, sc2));
                float e0 = __expf(sc0 - mx), e1 = __expf(sc1 - mx), e2 = __expf(sc2 - mx);
                float inv = 1.f / (e0 + e1 + e2);
                a_all[bb][n][0] = e0 * inv; a_all[bb][n][1] = e1 * inv; a_all[bb][n][2] = e2 * inv;
            }
        } else {
            #pragma unroll 1
            for (int rep = 0; rep < 2; ++rep) {
                int k = (rep == 0) ? wid : 0;
                if (rep == 1 && wid != 7) break;
                float ag[12];
                #pragma unroll
                for (int i = 0; i < 12; ++i) ag[i] = 0.f;
                int ch0 = k * 8 + chsub * 4;
                #pragma unroll
                for (int i = 0; i < 4; ++i) {
                    int ch = ch0 + i;
                    uint4 h0 = lds_h4[bp][ch], h1 = lds_h4[bp + 4][ch];
                    #pragma unroll
                    for (int j = 0; j < 6; ++j) {
                        uint4 w = lds_W[ch][16 + colsub + 8 * j];
                        ag[j]     = dot4(h0, w, ag[j]);
                        ag[6 + j] = dot4(h1, w, ag[6 + j]);
                    }
                }
                #pragma unroll
                for (int i = 0; i < 12; ++i) ag[i] += __shfl_xor(ag[i], 32);
                if (chsub == 0) {
                    #pragma unroll
                    for (int j = 0; j < 6; ++j) {
                        redH[k][colsub + 8 * j][bp]     = ag[j];
                        redH[k][colsub + 8 * j][bp + 4] = ag[6 + j];
                    }
                }
            }
        }
        __syncthreads();                                   // B4

        // ---- combine (waves1-6): ghsum + gxsum ; all waves: pack win t+1 ----
        if (tid >= 64 && tid < 448) {
            int idx = tid - 64;
            int col = idx >> 3, bb = idx & 7;
            float ghs = redH[0][col][bb];
            #pragma unroll
            for (int k = 1; k < 8; ++k) ghs += redH[k][col][bb];
            float gxs = 0.f;
            int half = bb >> 2, bq = bb & 3;
            #pragma unroll
            for (int g = 0; g < 3; ++g) {
                int sg = (t + 1 + g) % 3;
                #pragma unroll
                for (int k = 0; k < 8; ++k) {
                    fp16x2 uv = __builtin_bit_cast(fp16x2, u_pk[sg][k][col][bq]);
                    gxs += a_all[bb][k][g] * (float)uv[half];
                }
            }
            redQf[col * 8 + bb]       = ghs;
            redQf[384 + col * 8 + bb] = gxs;
        }
        {
            uint4 pk;
            pk.x = pack2f16(r3a.x, r3a.y); pk.y = pack2f16(r3a.z, r3a.w);
            pk.z = pack2f16(r3b.x, r3b.y); pk.w = pack2f16(r3b.z, r3b.w);
            lds_h4[wid][lane] = pk;    // safe: gh finished reading h at B4
        }
        __syncthreads();                                   // B5

        // ---- GRU pointwise + h publish ----
        if (tid < 128) {
            int c = tid >> 3, bb = tid & 7;
            float ghr = redQf[c * 8 + bb]        + bhr;
            float ghz = redQf[(16 + c) * 8 + bb] + bhz;
            float ghn = redQf[(32 + c) * 8 + bb] + bhn;
            float gxr = redQf[384 + c * 8 + bb]        + bxr;
            float gxz = redQf[384 + (16 + c) * 8 + bb] + bxz;
            float gxn = redQf[384 + (32 + c) * 8 + bb] + bxn;
            float r = fsigmoid(gxr + ghr);
            float z = fsigmoid(gxz + ghz);
            float n = ftanhf(gxn + r * ghn);
            float hnew = (1.f - z) * n + z * hprev;
            hprev = hnew; pooledv += hnew;
            float hnext = __shfl_down(hnew, 8);
            if ((c & 1) == 0)
                a_st(&Hbuf[(size_t)par * 16384 + (gid * 8 + bb) * 256 + bid * 8 + (c >> 1)],
                     pack2f16(hnew, hnext));
        }
        vmem_fence();
        __syncthreads();                                   // B6
        if (tid == 0) a_st(&flagH[gid * 32 + bid], (unsigned)(t + 1));
    }

    // ======== epilogue: pooled -> relu -> FC1 -> FC2 ========
    float* stage = (float*)&lds_W[0][0];
    if (tid < 128) {
        int c = tid >> 3, bb = tid & 7;
        a_stf(&pooled_g[(gid * 8 + bb) * 512 + bid * 16 + c], fmaxf(pooledv, 0.f));
    }
    vmem_fence();
    __syncthreads();
    if (tid == 0) a_st(&flagS[gid * 32 + bid], (unsigned)(SEQ + 1));
    if (wid == 0) {
        bool done = lane >= 32;
        while (!__all(done)) {
            if (!done) done = (a_ld(&flagS[gid * 32 + lane]) >= (unsigned)(SEQ + 1));
            if (!__all(done)) __builtin_amdgcn_s_sleep(1);
        }
    }
    __syncthreads();

    for (int i = tid; i < 8 * 512; i += THREADS) {
        int bb = i >> 9, k = i & 511;
        stage[bb * 512 + k] = a_ldf(&pooled_g[(gid * 8 + bb) * 512 + k]);
    }
    __syncthreads();

    if (tid < 128) {
        int c = tid >> 3, bb = tid & 7;
        int cg = bid * 16 + c;
        const float* pr = stage + bb * 512;
        float acc1 = b1[cg];
        for (int k = 0; k < 512; ++k) acc1 += pr[k] * W1[(size_t)k * 512 + cg];
        a_stf(&fc1_g[(gid * 8 + bb) * 512 + cg], acc1);
    }
    vmem_fence();
    __syncthreads();
    if (tid == 0) a_st(&flagH[gid * 32 + bid], (unsigned)(SEQ + 2));

    if (bid == 0) {
        if (wid == 0) {
            bool done = lane >= 32;
            while (!__all(done)) {
                if (!done) done = (a_ld(&flagH[gid * 32 + lane]) >= (unsigned)(SEQ + 2));
                if (!__all(done)) __builtin_amdgcn_s_sleep(1);
            }
        }
        __syncthreads();
        for (int i = tid; i < 8 * 512; i += THREADS) {
            int bb = i >> 9, k = i & 511;
            stage[bb * 512 + k] = a_ldf(&fc1_g[(gid * 8 + bb) * 512 + k]);
        }
        __syncthreads();
        if (tid < 80) {
            int bb = tid / 10, cls = tid - bb * 10;
            const float* fr = stage + bb * 512;
            float a2 = b2[cls];
            for (int k = 0; k < 512; ++k) a2 += fr[k] * W2[k * 10 + cls];
            out[(gid * 8 + bb) * 10 + cls] = a2;
        }
    }
}

extern "C" void kernel_launch(void* const* d_in, const int* in_sizes, int n_in,
                              void* d_out, int out_size, void* d_ws, size_t ws_size,
                              hipStream_t stream) {
    const int*   x   = (const int*)d_in[0];
    const float* emb = (const float*)d_in[1];
    const float* Wq  = (const float*)d_in[2];
    const float* Wx  = (const float*)d_in[3];
    const float* Wh  = (const float*)d_in[4];
    const float* bx  = (const float*)d_in[5];
    const float* bh  = (const float*)d_in[6];
    const float* W1  = (const float*)d_in[7];
    const float* b1  = (const float*)d_in[8];
    const float* W2  = (const float*)d_in[9];
    const float* b2  = (const float*)d_in[10];
    uint4* wsp = (uint4*)d_ws;
    float* outp = (float*)d_out;

    hipLaunchKernelGGL(pack_weights, dim3(896), dim3(256), 0, stream, Wq, Wx, Wh, wsp);
    hipMemsetAsync((char*)d_ws + SYNC_OFF, 0, 182272, stream);

    void* args[] = { (void*)&x, (void*)&emb, (void*)&wsp, (void*)&bx, (void*)&bh,
                     (void*)&W1, (void*)&b1, (void*)&W2, (void*)&b2, (void*)&outp };
    hipError_t e = hipLaunchCooperativeKernel((void*)gru_scan, dim3(256), dim3(THREADS),
                                              args, 0, stream);
    if (e != hipSuccess) {
        hipLaunchKernelGGL(gru_scan, dim3(256), dim3(THREADS), 0, stream,
                           x, emb, wsp, bx, bh, W1, b1, W2, b2, outp);
    }
}